// Round 1
// baseline (105.638 us; speedup 1.0000x reference)
//
#include <hip/hip_runtime.h>
#include <math.h>

constexpr int Bn = 16, Cn = 192, Tn = 4096;
constexpr int NS = 4, CG = Cn / NS;            // 48 groups
constexpr long long ZSZ = (long long)Bn * Cn * Tn;  // 12,582,912

// ---------------------------------------------------------------------------
// z[b, co, t] = sum_i W[o,i] * x[b, ch(i), t] * mask[b,t]
// where for group g in [0,48): ch(0)=2g, ch(1)=2g+1, ch(2)=96+2g, ch(3)=97+2g
// and output channel co uses the same mapping with o.
// ---------------------------------------------------------------------------
__global__ __launch_bounds__(256) void mix_kernel(
    const float* __restrict__ x, const float* __restrict__ mask,
    const float* __restrict__ w, float* __restrict__ out)
{
    __shared__ float ws[16];
    if (threadIdx.x < 16) ws[threadIdx.x] = w[threadIdx.x];
    __syncthreads();

    const int tv = blockIdx.x * blockDim.x + threadIdx.x;  // float4 idx in [0, Tn/4)
    const int g  = blockIdx.y;
    const int b  = blockIdx.z;

    const size_t base = (size_t)b * Cn * Tn;
    const int ch0 = 2 * g;
    const int ch1 = 2 * g + 1;
    const int ch2 = 96 + 2 * g;
    const int ch3 = 96 + 2 * g + 1;

    const float4* xp0 = (const float4*)(x + base + (size_t)ch0 * Tn);
    const float4* xp1 = (const float4*)(x + base + (size_t)ch1 * Tn);
    const float4* xp2 = (const float4*)(x + base + (size_t)ch2 * Tn);
    const float4* xp3 = (const float4*)(x + base + (size_t)ch3 * Tn);
    const float4* mp  = (const float4*)(mask + (size_t)b * Tn);

    const float4 a0 = xp0[tv];
    const float4 a1 = xp1[tv];
    const float4 a2 = xp2[tv];
    const float4 a3 = xp3[tv];
    const float4 m  = mp[tv];

    float4* op0 = (float4*)(out + base + (size_t)ch0 * Tn);
    float4* op1 = (float4*)(out + base + (size_t)ch1 * Tn);
    float4* op2 = (float4*)(out + base + (size_t)ch2 * Tn);
    float4* op3 = (float4*)(out + base + (size_t)ch3 * Tn);

#define MIX(o)                                                                   \
    {                                                                            \
        const float w0 = ws[(o)*4 + 0], w1 = ws[(o)*4 + 1],                      \
                    w2 = ws[(o)*4 + 2], w3 = ws[(o)*4 + 3];                      \
        float4 r;                                                                \
        r.x = (w0 * a0.x + w1 * a1.x + w2 * a2.x + w3 * a3.x) * m.x;             \
        r.y = (w0 * a0.y + w1 * a1.y + w2 * a2.y + w3 * a3.y) * m.y;             \
        r.z = (w0 * a0.z + w1 * a1.z + w2 * a2.z + w3 * a3.z) * m.z;             \
        r.w = (w0 * a0.w + w1 * a1.w + w2 * a2.w + w3 * a3.w) * m.w;             \
        op##o[tv] = r;                                                           \
    }
    MIX(0)
    MIX(1)
    MIX(2)
    MIX(3)
#undef MIX
}

// ---------------------------------------------------------------------------
// logdet[b] = log(det W) * (C/NS) * sum_t mask[b, t]
// One block per batch; det of the 4x4 computed in double (cofactor form).
// ---------------------------------------------------------------------------
__global__ __launch_bounds__(256) void logdet_kernel(
    const float* __restrict__ mask, const float* __restrict__ w,
    float* __restrict__ out)
{
    const int b = blockIdx.x;
    const float* mp = mask + (size_t)b * Tn;

    float s = 0.f;
    for (int i = threadIdx.x; i < Tn; i += 256) s += mp[i];
    for (int off = 32; off; off >>= 1) s += __shfl_down(s, off, 64);

    __shared__ float partial[4];
    const int wave = threadIdx.x >> 6;
    const int lane = threadIdx.x & 63;
    if (lane == 0) partial[wave] = s;
    __syncthreads();

    if (threadIdx.x == 0) {
        const float total = partial[0] + partial[1] + partial[2] + partial[3];
        double a[16];
#pragma unroll
        for (int i = 0; i < 16; ++i) a[i] = (double)w[i];
        const double s0 = a[0]*a[5]  - a[4]*a[1];
        const double s1 = a[0]*a[6]  - a[4]*a[2];
        const double s2 = a[0]*a[7]  - a[4]*a[3];
        const double s3 = a[1]*a[6]  - a[5]*a[2];
        const double s4 = a[1]*a[7]  - a[5]*a[3];
        const double s5 = a[2]*a[7]  - a[6]*a[3];
        const double c5 = a[10]*a[15] - a[14]*a[11];
        const double c4 = a[9]*a[15]  - a[13]*a[11];
        const double c3 = a[9]*a[14]  - a[13]*a[10];
        const double c2 = a[8]*a[15]  - a[12]*a[11];
        const double c1 = a[8]*a[14]  - a[12]*a[10];
        const double c0 = a[8]*a[13]  - a[12]*a[9];
        const double det = s0*c5 - s1*c4 + s2*c3 + s3*c2 - s4*c1 + s5*c0;
        const double ld  = log(fabs(det)) * (double)(Cn / NS) * (double)total;
        out[ZSZ + b] = (float)ld;
    }
}

extern "C" void kernel_launch(void* const* d_in, const int* in_sizes, int n_in,
                              void* d_out, int out_size, void* d_ws, size_t ws_size,
                              hipStream_t stream) {
    const float* x    = (const float*)d_in[0];
    const float* mask = (const float*)d_in[1];
    const float* w    = (const float*)d_in[2];
    float* out = (float*)d_out;

    // (Tn/4)/256 = 4 blocks along t, 48 groups, 16 batches -> 3072 blocks
    mix_kernel<<<dim3(4, CG, Bn), 256, 0, stream>>>(x, mask, w, out);
    logdet_kernel<<<Bn, 256, 0, stream>>>(mask, w, out);
}

// Round 2
// 101.502 us; speedup vs baseline: 1.0407x; 1.0407x over previous
//
#include <hip/hip_runtime.h>
#include <math.h>

constexpr int Bn = 16, Cn = 192, Tn = 4096;
constexpr int NS = 4, CG = Cn / NS;            // 48 groups
constexpr long long ZSZ = (long long)Bn * Cn * Tn;  // 12,582,912

// ---------------------------------------------------------------------------
// z[b, co, t] = sum_i W[o,i] * x[b, ch(i), t] * mask[b,t]
// where for group g in [0,48): ch(0)=2g, ch(1)=2g+1, ch(2)=96+2g, ch(3)=97+2g
// and output channel co uses the same mapping with o.
//
// Fused: the 16 blocks with (blockIdx.x==0, blockIdx.y==0) — one per batch —
// additionally reduce the (L2-hot) mask row and write
//   logdet[b] = log(det W) * (C/NS) * sum_t mask[b,t]
// at out[ZSZ + b]. det computed in double (cofactor form) by thread 0;
// the ~2e5x multiplier amplifies det rounding, fp64 makes it exact enough.
// ---------------------------------------------------------------------------
__global__ __launch_bounds__(256) void mix_kernel(
    const float* __restrict__ x, const float* __restrict__ mask,
    const float* __restrict__ w, float* __restrict__ out)
{
    __shared__ float ws[16];
    if (threadIdx.x < 16) ws[threadIdx.x] = w[threadIdx.x];
    __syncthreads();

    const int tv = blockIdx.x * blockDim.x + threadIdx.x;  // float4 idx in [0, Tn/4)
    const int g  = blockIdx.y;
    const int b  = blockIdx.z;

    const size_t base = (size_t)b * Cn * Tn;
    const int ch0 = 2 * g;
    const int ch1 = 2 * g + 1;
    const int ch2 = 96 + 2 * g;
    const int ch3 = 96 + 2 * g + 1;

    const float4* xp0 = (const float4*)(x + base + (size_t)ch0 * Tn);
    const float4* xp1 = (const float4*)(x + base + (size_t)ch1 * Tn);
    const float4* xp2 = (const float4*)(x + base + (size_t)ch2 * Tn);
    const float4* xp3 = (const float4*)(x + base + (size_t)ch3 * Tn);
    const float4* mp  = (const float4*)(mask + (size_t)b * Tn);

    const float4 a0 = xp0[tv];
    const float4 a1 = xp1[tv];
    const float4 a2 = xp2[tv];
    const float4 a3 = xp3[tv];
    const float4 m  = mp[tv];

    float4* op0 = (float4*)(out + base + (size_t)ch0 * Tn);
    float4* op1 = (float4*)(out + base + (size_t)ch1 * Tn);
    float4* op2 = (float4*)(out + base + (size_t)ch2 * Tn);
    float4* op3 = (float4*)(out + base + (size_t)ch3 * Tn);

#define MIX(o)                                                                   \
    {                                                                            \
        const float w0 = ws[(o)*4 + 0], w1 = ws[(o)*4 + 1],                      \
                    w2 = ws[(o)*4 + 2], w3 = ws[(o)*4 + 3];                      \
        float4 r;                                                                \
        r.x = (w0 * a0.x + w1 * a1.x + w2 * a2.x + w3 * a3.x) * m.x;             \
        r.y = (w0 * a0.y + w1 * a1.y + w2 * a2.y + w3 * a3.y) * m.y;             \
        r.z = (w0 * a0.z + w1 * a1.z + w2 * a2.z + w3 * a3.z) * m.z;             \
        r.w = (w0 * a0.w + w1 * a1.w + w2 * a2.w + w3 * a3.w) * m.w;             \
        op##o[tv] = r;                                                           \
    }
    MIX(0)
    MIX(1)
    MIX(2)
    MIX(3)
#undef MIX

    // ---- fused logdet: one block per batch handles the full mask row ----
    if (blockIdx.x != 0 || blockIdx.y != 0) return;

    float s = 0.f;
    const float4* mr = (const float4*)(mask + (size_t)b * Tn);
    for (int i = threadIdx.x; i < Tn / 4; i += 256) {
        const float4 mv = mr[i];            // L2-hot: every block of batch b reads this row
        s += (mv.x + mv.y) + (mv.z + mv.w);
    }
    for (int off = 32; off; off >>= 1) s += __shfl_down(s, off, 64);

    __shared__ float partial[4];
    const int wave = threadIdx.x >> 6;
    const int lane = threadIdx.x & 63;
    if (lane == 0) partial[wave] = s;
    __syncthreads();

    if (threadIdx.x == 0) {
        const float total = partial[0] + partial[1] + partial[2] + partial[3];
        double a[16];
#pragma unroll
        for (int i = 0; i < 16; ++i) a[i] = (double)ws[i];
        const double s0 = a[0]*a[5]  - a[4]*a[1];
        const double s1 = a[0]*a[6]  - a[4]*a[2];
        const double s2 = a[0]*a[7]  - a[4]*a[3];
        const double s3 = a[1]*a[6]  - a[5]*a[2];
        const double s4 = a[1]*a[7]  - a[5]*a[3];
        const double s5 = a[2]*a[7]  - a[6]*a[3];
        const double c5 = a[10]*a[15] - a[14]*a[11];
        const double c4 = a[9]*a[15]  - a[13]*a[11];
        const double c3 = a[9]*a[14]  - a[13]*a[10];
        const double c2 = a[8]*a[15]  - a[12]*a[11];
        const double c1 = a[8]*a[14]  - a[12]*a[10];
        const double c0 = a[8]*a[13]  - a[12]*a[9];
        const double det = s0*c5 - s1*c4 + s2*c3 + s3*c2 - s4*c1 + s5*c0;
        const double ld  = log(fabs(det)) * (double)(Cn / NS) * (double)total;
        out[ZSZ + b] = (float)ld;
    }
}

extern "C" void kernel_launch(void* const* d_in, const int* in_sizes, int n_in,
                              void* d_out, int out_size, void* d_ws, size_t ws_size,
                              hipStream_t stream) {
    const float* x    = (const float*)d_in[0];
    const float* mask = (const float*)d_in[1];
    const float* w    = (const float*)d_in[2];
    float* out = (float*)d_out;

    // (Tn/4)/256 = 4 blocks along t, 48 groups, 16 batches -> 3072 blocks
    mix_kernel<<<dim3(4, CG, Bn), 256, 0, stream>>>(x, mask, w, out);
}